// Round 4
// baseline (219.930 us; speedup 1.0000x reference)
//
#include <hip/hip_runtime.h>
#include <hip/hip_bf16.h>

using u16 = unsigned short;
using u32 = unsigned int;
using short8  = __attribute__((ext_vector_type(8))) short;
using short4v = __attribute__((ext_vector_type(4))) short;
using floatx4 = __attribute__((ext_vector_type(4))) float;

#define TT 2048
#define CC 1024
#define HH 16
#define DD 64
#define BBATCH 2
#define MM (BBATCH*TT)   // 4096

// (1/sqrt(64)) * log2(e): folded into Q at projection epilogue; softmax uses exp2.
#define QSCALE 0.18033688011112042f

__device__ __forceinline__ u16 f2bf(float f) {
    u32 u = __float_as_uint(f);
    u += 0x7fffu + ((u >> 16) & 1u);   // RNE
    return (u16)(u >> 16);
}
__device__ __forceinline__ float bf2f(u16 s) {
    return __uint_as_float(((u32)s) << 16);
}
__device__ __forceinline__ float bpermf(float v, int srclane) {
    return __int_as_float(__builtin_amdgcn_ds_bpermute(srclane * 4, __float_as_int(v)));
}
// async global->LDS, 16B per lane (m97 pattern): lds must be wave-uniform base + lane*16
__device__ __forceinline__ void gll16(const u16* g, u16* l) {
    __builtin_amdgcn_global_load_lds((const __attribute__((address_space(1))) void*)g,
                                     (__attribute__((address_space(3))) void*)l, 16, 0, 0);
}

// ---------------- fused cast fp32 -> bf16 (x + 4 weights, one launch) ----------------
__global__ __launch_bounds__(256) void cast_all(const float* __restrict__ x,
    const float* __restrict__ Wq, const float* __restrict__ Wk,
    const float* __restrict__ Wv, const float* __restrict__ Wo,
    u16* __restrict__ xb, u16* __restrict__ wqb, u16* __restrict__ wkb,
    u16* __restrict__ wvb, u16* __restrict__ wob)
{
    int i = blockIdx.x * 256 + threadIdx.x;   // 0 .. 2097151
    const float* src; u16* dst; int off;
    if (i < 1048576) { src = x; dst = xb; off = i; }
    else {
        int j = i - 1048576;
        int s = j >> 18;           // 0..3
        off = j & 262143;
        src = (s == 0) ? Wq : (s == 1) ? Wk : (s == 2) ? Wv : Wo;
        dst = (s == 0) ? wqb : (s == 1) ? wkb : (s == 2) ? wvb : wob;
    }
    float4 v = ((const float4*)src)[off];
    u16 r[4];
    r[0] = f2bf(v.x); r[1] = f2bf(v.y); r[2] = f2bf(v.z); r[3] = f2bf(v.w);
    ((ushort4*)dst)[off] = *(ushort4*)r;
}

// ---------------- V transpose: [BH][T][D] -> [BH][D][T] ----------------
__global__ __launch_bounds__(256) void transpose_v(const u16* __restrict__ v, u16* __restrict__ vt) {
    __shared__ u16 tile[64][72];
    int bh = blockIdx.y;
    int t0 = blockIdx.x * 64;
    int r = threadIdx.x >> 2;
    int c = (threadIdx.x & 3) * 16;
    const u16* src = v + ((size_t)bh * TT + t0 + r) * DD + c;
    *(uint4*)&tile[r][c]     = *(const uint4*)src;
    *(uint4*)&tile[r][c + 8] = *(const uint4*)(src + 8);
    __syncthreads();
    u16 tmp[16];
#pragma unroll
    for (int j = 0; j < 16; ++j) tmp[j] = tile[c + j][r];
    u16* dst = vt + ((size_t)bh * DD + r) * TT + t0 + c;
    *(uint4*)dst       = *(uint4*)&tmp[0];
    *(uint4*)(dst + 8) = *(uint4*)&tmp[8];
}

// ---------------- qkv GEMM: 128x128 tile (m97 structure) ----------------
__global__ __launch_bounds__(256, 2) void qkv_gemm(const u16* __restrict__ xb,
    const u16* __restrict__ wq, const u16* __restrict__ wk, const u16* __restrict__ wv,
    const float* __restrict__ bq, const float* __restrict__ bk, const float* __restrict__ bv,
    u16* __restrict__ q, u16* __restrict__ k, u16* __restrict__ v)
{
    __shared__ u16 As[128*32];
    __shared__ u16 Bs[128*32];
    const int K = CC;
    int z = blockIdx.z;
    const u16* W = (z == 0) ? wq : (z == 1) ? wk : wv;
    const float* bias = (z == 0) ? bq : (z == 1) ? bk : bv;
    u16* outp = (z == 0) ? q : (z == 1) ? k : v;
    float outscale = (z == 0) ? QSCALE : 1.0f;

    int tid = threadIdx.x;
    int m0 = blockIdx.y * 128;
    int n0 = blockIdx.x * 128;
    int lane = tid & 63;
    int w  = tid >> 6;
    int wm = (w >> 1) * 64;
    int wn = (w & 1) * 64;
    int lm = lane & 15;
    int lq = lane >> 4;

    floatx4 acc[4][4];
#pragma unroll
    for (int i = 0; i < 4; ++i)
#pragma unroll
        for (int j = 0; j < 4; ++j)
            acc[i][j] = (floatx4){0.f, 0.f, 0.f, 0.f};

    const u16* ag = xb + (size_t)(m0 + (tid >> 2)) * K + (tid & 3) * 8;
    const u16* wg = W  + (size_t)(n0 + (tid >> 2)) * K + (tid & 3) * 8;
    u16* asl = As + tid * 8;
    u16* bsl = Bs + tid * 8;

    for (int k0 = 0; k0 < K; k0 += 32) {
        __syncthreads();
        gll16(ag + k0,           asl);
        gll16(ag + 64*K + k0,    asl + 2048);
        gll16(wg + k0,           bsl);
        gll16(wg + 64*K + k0,    bsl + 2048);
        __syncthreads();
        short8 af[4], bfr[4];
#pragma unroll
        for (int t = 0; t < 4; ++t) {
            af[t]  = *(const short8*)(As + (wm + t*16 + lm)*32 + lq*8);
            bfr[t] = *(const short8*)(Bs + (wn + t*16 + lm)*32 + lq*8);
        }
#pragma unroll
        for (int i = 0; i < 4; ++i)
#pragma unroll
            for (int j = 0; j < 4; ++j)
                acc[i][j] = __builtin_amdgcn_mfma_f32_16x16x32_bf16(af[i], bfr[j], acc[i][j], 0, 0, 0);
    }

#pragma unroll
    for (int j = 0; j < 4; ++j) {
        int col = n0 + wn + j*16 + lm;
        float bv2 = bias[col];
#pragma unroll
        for (int i = 0; i < 4; ++i) {
#pragma unroll
            for (int r = 0; r < 4; ++r) {
                int row = m0 + wm + i*16 + lq*4 + r;
                float val = (acc[i][j][r] + bv2) * outscale;
                int b_ = row >> 11, t_ = row & (TT-1);
                int h_ = col >> 6,  d_ = col & 63;
                outp[(((size_t)(b_*HH + h_) * TT + t_) * DD) + d_] = f2bf(val);
            }
        }
    }
}

// ---------------- O GEMM: 128x64 tile (512 blocks, 2/CU) ----------------
__global__ __launch_bounds__(256, 4) void o_gemm(const u16* __restrict__ A, const u16* __restrict__ W,
                                                 const float* __restrict__ bias, float* __restrict__ outp)
{
    __shared__ u16 As[128*32];
    __shared__ u16 Bs[64*32];
    const int K = CC;
    int tid = threadIdx.x;
    int m0 = blockIdx.y * 128;
    int n0 = blockIdx.x * 64;
    int lane = tid & 63;
    int w  = tid >> 6;          // 4 waves: rows w*32..+31
    int lm = lane & 15;
    int lq = lane >> 4;

    floatx4 acc[2][4];
#pragma unroll
    for (int i = 0; i < 2; ++i)
#pragma unroll
        for (int j = 0; j < 4; ++j)
            acc[i][j] = (floatx4){0.f, 0.f, 0.f, 0.f};

    const u16* ag = A + (size_t)(m0 + (tid >> 2)) * K + (tid & 3) * 8;
    const u16* wg = W + (size_t)(n0 + (tid >> 2)) * K + (tid & 3) * 8;
    u16* asl = As + tid * 8;
    u16* bsl = Bs + tid * 8;

    for (int k0 = 0; k0 < K; k0 += 32) {
        __syncthreads();
        gll16(ag + k0,        asl);
        gll16(ag + 64*K + k0, asl + 2048);
        gll16(wg + k0,        bsl);
        __syncthreads();
        short8 af[2], bfr[4];
#pragma unroll
        for (int i = 0; i < 2; ++i)
            af[i] = *(const short8*)(As + (w*32 + i*16 + lm)*32 + lq*8);
#pragma unroll
        for (int j = 0; j < 4; ++j)
            bfr[j] = *(const short8*)(Bs + (j*16 + lm)*32 + lq*8);
#pragma unroll
        for (int i = 0; i < 2; ++i)
#pragma unroll
            for (int j = 0; j < 4; ++j)
                acc[i][j] = __builtin_amdgcn_mfma_f32_16x16x32_bf16(af[i], bfr[j], acc[i][j], 0, 0, 0);
    }

#pragma unroll
    for (int j = 0; j < 4; ++j) {
        int col = n0 + j*16 + lm;
        float bv2 = bias[col];
#pragma unroll
        for (int i = 0; i < 2; ++i) {
#pragma unroll
            for (int r = 0; r < 4; ++r) {
                int row = m0 + w*32 + i*16 + lq*4 + r;
                outp[(size_t)row * CC + col] = acc[i][j][r] + bv2;
            }
        }
    }
}

// ---------------- MFMA flash attention, causal ----------------
// S^T = K·Q^T so P lands in A-operand layout of mfma 16x16x16. Br=64 (2 waves x 32 rows),
// Bc=64, 1024 blocks. K staged via global_load_lds (unpadded [64][64]); V^T staged via
// VGPR with PV swizzle (padded 72).
__global__ __launch_bounds__(128, 2) void attn_mfma(const u16* __restrict__ qg, const u16* __restrict__ kg,
                                                    const u16* __restrict__ vtg, u16* __restrict__ attnb)
{
    __shared__ u16 Ks[64*64];   // [key][d] unpadded (gll16 target)
    __shared__ u16 Vs[64*72];   // [d][key-swizzled], pad 72

    int tid = threadIdx.x;      // 0..127
    int lane = tid & 63;
    int w = tid >> 6;           // 0..1: rows w*32..+31
    int lm = lane & 15;
    int lq = lane >> 4;
    int qt = 31 - (int)blockIdx.x;   // heavy tiles first
    int bh = blockIdx.y;
    int b_ = bh >> 4, h_ = bh & 15;
    int q0 = qt * 64;

    const size_t basek  = (size_t)bh * TT * DD;
    const size_t basevt = (size_t)bh * DD * TT;

    // Q fragments (B-operand for S^T): aq[i][ks] = Q[q0+w*32+i*16+lm][ks*32+lq*8 ..+7]
    short8 aq[2][2];
    {
        const u16* qbase = qg + basek + (size_t)(q0 + w*32 + lm) * DD + lq*8;
#pragma unroll
        for (int i = 0; i < 2; ++i)
#pragma unroll
            for (int ks = 0; ks < 2; ++ks)
                aq[i][ks] = *(const short8*)(qbase + i*16*DD + ks*32);
    }

    floatx4 oacc[2][4];
#pragma unroll
    for (int i = 0; i < 2; ++i)
#pragma unroll
        for (int j = 0; j < 4; ++j)
            oacc[i][j] = (floatx4){0.f, 0.f, 0.f, 0.f};
    float mrun[2] = {-3e38f, -3e38f};
    float lrun[2] = {0.f, 0.f};

    // --- staging addresses ---
    // K via gll16: 4 call sites; site c covers rows w*32+c*8 .. +7
    const u16* kgl = kg + basek + (size_t)(w*32 + (lane >> 3)) * DD + (lane & 7) * 8;
    u16* kls = Ks + w*32*64 + lane*8;
    // V via VGPR swizzle: thread t: d-row = t>>1, key-groups kb = (t&1)*2, +1
    int vrow = tid >> 1;
    int kbv  = (tid & 1) * 2;
    const u16* vsrc = vtg + basevt + (size_t)vrow * TT + kbv*16;
    u16* vdst0 = Vs + vrow*72 + (kbv>>1)*32 + (kbv&1)*4;            // kb = kbv
    u16* vdst1 = Vs + vrow*72 + ((kbv+1)>>1)*32 + ((kbv+1)&1)*4;    // kb = kbv+1

    int nkt = qt + 1;

    for (int kt = 0; kt < nkt; ++kt) {
        // prefetch V to regs (overlaps previous compute)
        uint4 v0a = *(const uint4*)(vsrc + kt*64);
        uint4 v0b = *(const uint4*)(vsrc + kt*64 + 8);
        uint4 v1a = *(const uint4*)(vsrc + kt*64 + 16);
        uint4 v1b = *(const uint4*)(vsrc + kt*64 + 24);
        __syncthreads();   // previous iteration's LDS reads complete
        // K: async global->LDS
#pragma unroll
        for (int c = 0; c < 4; ++c)
            gll16(kgl + (size_t)(kt*64 + c*8) * DD, kls + c*512);
        // V: swizzled LDS writes
        *(uint2*)(vdst0)      = make_uint2(v0a.x, v0a.y);
        *(uint2*)(vdst0 + 8)  = make_uint2(v0a.z, v0a.w);
        *(uint2*)(vdst0 + 16) = make_uint2(v0b.x, v0b.y);
        *(uint2*)(vdst0 + 24) = make_uint2(v0b.z, v0b.w);
        *(uint2*)(vdst1)      = make_uint2(v1a.x, v1a.y);
        *(uint2*)(vdst1 + 8)  = make_uint2(v1a.z, v1a.w);
        *(uint2*)(vdst1 + 16) = make_uint2(v1b.x, v1b.y);
        *(uint2*)(vdst1 + 24) = make_uint2(v1b.z, v1b.w);
        __syncthreads();   // drains vmcnt (gll16) + lgkm

        // ---- S^T = K Q^T : col=lm -> q, row=lq*4+r -> key ----
        floatx4 st[2][4];
#pragma unroll
        for (int i = 0; i < 2; ++i)
#pragma unroll
            for (int jn = 0; jn < 4; ++jn)
                st[i][jn] = (floatx4){0.f, 0.f, 0.f, 0.f};
#pragma unroll
        for (int jn = 0; jn < 4; ++jn) {
            short8 kf0 = *(const short8*)&Ks[(jn*16 + lm)*64 + lq*8];
            short8 kf1 = *(const short8*)&Ks[(jn*16 + lm)*64 + 32 + lq*8];
#pragma unroll
            for (int i = 0; i < 2; ++i) {
                st[i][jn] = __builtin_amdgcn_mfma_f32_16x16x32_bf16(kf0, aq[i][0], st[i][jn], 0, 0, 0);
                st[i][jn] = __builtin_amdgcn_mfma_f32_16x16x32_bf16(kf1, aq[i][1], st[i][jn], 0, 0, 0);
            }
        }

        int kbase = kt*64;
        short4v ap[2][4];
#pragma unroll
        for (int i = 0; i < 2; ++i) {
            int qrow = q0 + w*32 + i*16 + lm;
            if (kbase + 63 > q0 + w*32 + i*16) {   // diagonal tile only
#pragma unroll
                for (int jn = 0; jn < 4; ++jn)
#pragma unroll
                    for (int r = 0; r < 4; ++r) {
                        int key = kbase + jn*16 + lq*4 + r;
                        if (key > qrow) st[i][jn][r] = -__builtin_inff();
                    }
            }
            float mx = st[i][0][0];
#pragma unroll
            for (int jn = 0; jn < 4; ++jn)
#pragma unroll
                for (int r = 0; r < 4; ++r) mx = fmaxf(mx, st[i][jn][r]);
            mx = fmaxf(mx, __shfl_xor(mx, 16));
            mx = fmaxf(mx, __shfl_xor(mx, 32));
            float mold = mrun[i];
            float newm = fmaxf(mold, mx);
            mrun[i] = newm;
            float psum = 0.f;
#pragma unroll
            for (int jn = 0; jn < 4; ++jn)
#pragma unroll
                for (int r = 0; r < 4; ++r) {
                    float pe = __builtin_amdgcn_exp2f(st[i][jn][r] - newm);
                    st[i][jn][r] = pe;
                    psum += pe;
                }
            psum += __shfl_xor(psum, 16);
            psum += __shfl_xor(psum, 32);
            float alpha = __builtin_amdgcn_exp2f(mold - newm);
            lrun[i] = lrun[i]*alpha + psum;
#pragma unroll
            for (int jn = 0; jn < 4; ++jn) {
                u32 lo = __builtin_amdgcn_perm(__float_as_uint(st[i][jn][1]),
                                               __float_as_uint(st[i][jn][0]), 0x07060302u);
                u32 hi = __builtin_amdgcn_perm(__float_as_uint(st[i][jn][3]),
                                               __float_as_uint(st[i][jn][2]), 0x07060302u);
                uint2 pk = make_uint2(lo, hi);
                ap[i][jn] = __builtin_bit_cast(short4v, pk);
            }
            if (__ballot(newm != mold)) {
                float ar[4];
#pragma unroll
                for (int r = 0; r < 4; ++r) ar[r] = bpermf(alpha, lq*4 + r);
#pragma unroll
                for (int jd = 0; jd < 4; ++jd)
#pragma unroll
                    for (int r = 0; r < 4; ++r) oacc[i][jd][r] *= ar[r];
            }
        }

        // ---- O += P V via 16x16x16 (A=P regs, B=V^T swizzled LDS) ----
#pragma unroll
        for (int p2 = 0; p2 < 2; ++p2) {
#pragma unroll
            for (int jd = 0; jd < 4; ++jd) {
                short8 vb = *(const short8*)&Vs[(jd*16 + lm)*72 + p2*32 + lq*8];
                short4v blo, bhi;
#pragma unroll
                for (int j = 0; j < 4; ++j) { blo[j] = vb[j]; bhi[j] = vb[j+4]; }
#pragma unroll
                for (int i = 0; i < 2; ++i) {
                    oacc[i][jd] = __builtin_amdgcn_mfma_f32_16x16x16bf16_1k(ap[i][2*p2],   blo, oacc[i][jd], 0, 0, 0);
                    oacc[i][jd] = __builtin_amdgcn_mfma_f32_16x16x16bf16_1k(ap[i][2*p2+1], bhi, oacc[i][jd], 0, 0, 0);
                }
            }
        }
    }

    // ---- epilogue: O / l -> attnb [B,T,C] bf16 ----
#pragma unroll
    for (int i = 0; i < 2; ++i) {
        float il[4];
#pragma unroll
        for (int r = 0; r < 4; ++r) il[r] = 1.f / bpermf(lrun[i], lq*4 + r);
#pragma unroll
        for (int r = 0; r < 4; ++r) {
            int qrow = q0 + w*32 + i*16 + lq*4 + r;
            u16* orow = attnb + ((size_t)(b_*TT + qrow)) * CC + h_*DD + lm;
#pragma unroll
            for (int jd = 0; jd < 4; ++jd)
                orow[jd*16] = f2bf(oacc[i][jd][r] * il[r]);
        }
    }
}

extern "C" void kernel_launch(void* const* d_in, const int* in_sizes, int n_in,
                              void* d_out, int out_size, void* d_ws, size_t ws_size,
                              hipStream_t stream)
{
    const float* x  = (const float*)d_in[0];
    const float* Wq = (const float*)d_in[1];
    const float* bq = (const float*)d_in[2];
    const float* Wk = (const float*)d_in[3];
    const float* bk = (const float*)d_in[4];
    const float* Wv = (const float*)d_in[5];
    const float* bv = (const float*)d_in[6];
    const float* Wo = (const float*)d_in[7];
    const float* bo = (const float*)d_in[8];
    float* out = (float*)d_out;

    char* ws = (char*)d_ws;
    u16* xb   = (u16*)(ws);                      // 8 MB (reused as attnb)
    u16* wqb  = (u16*)(ws + (size_t)( 8<<20));
    u16* wkb  = (u16*)(ws + (size_t)(10<<20));
    u16* wvb  = (u16*)(ws + (size_t)(12<<20));
    u16* wob  = (u16*)(ws + (size_t)(14<<20));
    u16* q    = (u16*)(ws + (size_t)(16<<20));   // [B,H,T,D], pre-scaled
    u16* k    = (u16*)(ws + (size_t)(24<<20));   // [B,H,T,D]
    u16* v    = (u16*)(ws + (size_t)(32<<20));   // [B,H,T,D]
    u16* vt   = (u16*)(ws + (size_t)(40<<20));   // [B,H,D,T]
    u16* attnb = xb;                             // xb dead after qkv_gemm

    cast_all<<<dim3(8192), dim3(256), 0, stream>>>(x, Wq, Wk, Wv, Wo, xb, wqb, wkb, wvb, wob);

    dim3 gq(CC/128, MM/128, 3);
    qkv_gemm<<<gq, dim3(256), 0, stream>>>(xb, wqb, wkb, wvb, bq, bk, bv, q, k, v);

    transpose_v<<<dim3(TT/64, BBATCH*HH), dim3(256), 0, stream>>>(v, vt);

    attn_mfma<<<dim3(TT/64, BBATCH*HH), dim3(128), 0, stream>>>(q, k, vt, attnb);

    dim3 go(CC/64, MM/128);
    o_gemm<<<go, dim3(256), 0, stream>>>(attnb, wob, bo, out);
}